// Round 4
// baseline (239.973 us; speedup 1.0000x reference)
//
#include <hip/hip_runtime.h>

// Problem: B=4, S=4096, H=16, D=128 -> C=2048, K=4. All fp32.
// out[b,h,s,d] = silu( bias[c] + sum_{k=0..3} w[c,k] * x[b, s-3+k, c] ), c = h*128+d
//
// Round-7: two container failures on the counted-vmcnt/inline-asm pipeline ->
// rebuild the SAME pipeline thesis using only round-1-proven constructs:
// global_load_lds + __syncthreads + plain stores. m97-verified overlap shape:
//   per tile: issue async prefetch(t+1) -> compute tile t from LDS -> barrier.
// The barrier's vmcnt(0) drain waits only the residual latency of prefetch(t+1),
// which flew under compute(t) (~5us BW-bound work vs ~0.4us HBM latency).
// Persistent 64-s strips: halo rows reused in the ring -> 1.05x logical reads.
// Ring-20 disjointness: prefetch(t+1) writes rows = [8t+11,8t+18] (mod 20),
// compute(t) reads [8t,8t+10]; row-diff in [1,18], never = 0 mod 20. Wrapping
// writers are prefetch(t+2), issued only after the barrier ending compute(t).

constexpr int Bb = 4, Ss = 4096, Hh = 16, Dd = 128, Cc = 2048, Kk = 4;
constexpr int SEQ  = 8;                  // s positions per tile
constexpr int CPB  = 1024;               // channels per block (256 thr x 4)
constexpr int TPB  = 8;                  // tiles per block (strip = 64 s)
constexpr int RING = 20;                 // LDS ring rows (80 KB)
constexpr int STRIPS = Ss / (SEQ * TPB); // 64

union F4 {
    float4 v;
    float f[4];
};

__device__ __forceinline__ void gload1k(const float* g, float* l) {
    // async global->LDS: 16B/lane, wave-uniform LDS base + HW lane*16.
    __builtin_amdgcn_global_load_lds(
        (const __attribute__((address_space(1))) void*)g,
        (__attribute__((address_space(3))) void*)l,
        16, 0, 0);
}

__global__ __launch_bounds__(256, 2) void titans_conv(
    const float* __restrict__ x,     // [B,S,C]
    const float* __restrict__ w,     // [C,K]
    const float* __restrict__ bias,  // [C]
    float* __restrict__ out)         // [B,H,S,D]
{
    __shared__ float lds[RING * CPB];            // 20 * 4KB = 80 KB

    const int t     = threadIdx.x;               // 0..255
    const int wv    = t >> 6;                    // wave 0..3
    const int ln    = t & 63;
    const int strip = (int)blockIdx.x;           // 0..63
    const int b     = (int)blockIdx.y;
    const int cb    = (int)blockIdx.z * CPB;
    const int c0    = cb + t * 4;
    const int S0    = strip * (SEQ * TPB);

    const float* xb = x + (size_t)b * Ss * Cc + cb;   // + s*Cc + q*256 + ln*4

    // ---- weights + bias (compiler inserts its own waits before first use) ----
    float wf[4][4], bv[4];
    {
        const float4* wp = (const float4*)(w + (size_t)c0 * Kk);
        F4 u0, u1, u2, u3, ub;
        u0.v = wp[0]; u1.v = wp[1]; u2.v = wp[2]; u3.v = wp[3];
        ub.v = *(const float4*)(bias + c0);
        #pragma unroll
        for (int k = 0; k < 4; ++k) {
            wf[0][k] = u0.f[k]; wf[1][k] = u1.f[k];
            wf[2][k] = u2.f[k]; wf[3][k] = u3.f[k];
        }
        #pragma unroll
        for (int j = 0; j < 4; ++j) bv[j] = ub.f[j];
    }

    // ---- prologue: stage rows lr = 0..10 (s = S0-3 .. S0+7) into slots 0..10 ----
    if (strip > 0) {                              // block-uniform branch
        #pragma unroll
        for (int k = 0; k < 11; ++k) {            // 44 segs, 11 per wave
            const int sidx = wv * 11 + k;
            const int lr = sidx >> 2, q = sidx & 3;
            gload1k(xb + (size_t)(S0 - 3 + lr) * Cc + q * 256 + ln * 4,
                    &lds[lr * CPB + q * 256]);
        }
    } else {                                      // zero halo rows lr=0..2
        #pragma unroll
        for (int r = 0; r < 3; ++r)
            *(float4*)&lds[r * CPB + t * 4] = float4{0.f, 0.f, 0.f, 0.f};
        #pragma unroll
        for (int k = 0; k < 8; ++k) {             // rows lr=3..10: 32 segs, 8/wave
            const int sidx = wv * 8 + k;
            const int lr = 3 + (sidx >> 2), q = sidx & 3;
            gload1k(xb + (size_t)(S0 - 3 + lr) * Cc + q * 256 + ln * 4,
                    &lds[lr * CPB + q * 256]);
        }
    }
    __syncthreads();                              // drain prologue, publish slots 0..10

    const int h = c0 >> 7;
    const int d = c0 & 127;
    float* orow = out + (((size_t)b * Hh + h) * Ss + S0) * Dd + d;

    #pragma unroll
    for (int tt = 0; tt < TPB; ++tt) {
        // ---- issue tile tt+1's 8 new rows (ring slots (8tt+11..8tt+18)%20),
        //      async; they fly under this tile's compute ----
        if (tt + 1 < TPB) {
            const int base = (8 * tt + 11) % RING;   // compile-time (unrolled)
            #pragma unroll
            for (int k = 0; k < 8; ++k) {
                const int rr = wv * 2 + (k >> 2);    // wave-uniform row 0..7
                const int q  = k & 3;
                int sl = base + rr;
                if (sl >= RING) sl -= RING;
                gload1k(xb + (size_t)(S0 + 8 + 8 * tt + rr) * Cc + q * 256 + ln * 4,
                        &lds[sl * CPB + q * 256]);
            }
        }

        // ---- compute tile tt from ring slots (8tt+i) % RING (published by the
        //      previous barrier; disjoint from the in-flight prefetch) ----
        F4 rows[SEQ + 3];
        #pragma unroll
        for (int i = 0; i < SEQ + 3; ++i) {
            const int sl = (8 * tt + i) % RING;      // compile-time
            rows[i].v = *(const float4*)&lds[sl * CPB + t * 4];
        }
        #pragma unroll
        for (int i = 0; i < SEQ; ++i) {
            F4 res;
            #pragma unroll
            for (int j = 0; j < 4; ++j) {
                float z = bv[j];
                z = fmaf(wf[j][0], rows[i + 0].f[j], z);
                z = fmaf(wf[j][1], rows[i + 1].f[j], z);
                z = fmaf(wf[j][2], rows[i + 2].f[j], z);
                z = fmaf(wf[j][3], rows[i + 3].f[j], z);
                float e = __expf(-z);
                res.f[j] = z * __builtin_amdgcn_rcpf(1.0f + e);
            }
            *(float4*)(orow + (size_t)(tt * SEQ + i) * Dd) = res.v;
        }

        __syncthreads();   // residual drain of prefetch(tt+1) + publish its slots
    }
}

extern "C" void kernel_launch(void* const* d_in, const int* in_sizes, int n_in,
                              void* d_out, int out_size, void* d_ws, size_t ws_size,
                              hipStream_t stream) {
    const float* x    = (const float*)d_in[0];   // hidden_states [B,S,H,D] = [B,S,C]
    const float* w    = (const float*)d_in[1];   // conv_weight [C,K]
    const float* bias = (const float*)d_in[2];   // conv_bias [C]
    float* out        = (float*)d_out;           // [B,H,S,D]

    dim3 grid(STRIPS, Bb, Cc / CPB);  // 64 x 4 x 2 = 512 blocks = 2/CU resident
    titans_conv<<<grid, 256, 0, stream>>>(x, w, bias, out);
}